// Round 14
// baseline (100.609 us; speedup 1.0000x reference)
//
#include <hip/hip_runtime.h>

#define J 17
#define F 128
#define TB 16          // batches per block (= MFMA N dim)

typedef __attribute__((ext_vector_type(4))) float f32x4;
typedef __attribute__((ext_vector_type(8))) short bf16x8;   // 8 bf16 in 4 VGPRs

// round-to-nearest-even f32 -> bf16
__device__ __forceinline__ unsigned short f2bf(float f) {
    unsigned u = __builtin_bit_cast(unsigned, f);
    u += 0x7fffu + ((u >> 16) & 1u);
    return (unsigned short)(u >> 16);
}
__device__ __forceinline__ float bf2f(unsigned short s) {
    return __builtin_bit_cast(float, (unsigned)s << 16);
}
// pack two f32 (raw bits) -> two bf16, round-half-up: 2 v_add + 1 v_perm
__device__ __forceinline__ unsigned pkbf(unsigned lo, unsigned hi) {
    return __builtin_amdgcn_perm(hi + 0x8000u, lo + 0x8000u, 0x07060302u);
}
__device__ __forceinline__ f32x4 fma4(float a, f32x4 v, f32x4 c) {
    f32x4 av = {a, a, a, a};
    return __builtin_elementwise_fma(av, v, c);
}
__device__ __forceinline__ f32x4 bf4(ushort4 u) {
    return (f32x4){bf2f(u.x), bf2f(u.y), bf2f(u.z), bf2f(u.w)};
}
__device__ __forceinline__ f32x4 mfma16(bf16x8 a, bf16x8 b, f32x4 c) {
    return __builtin_amdgcn_mfma_f32_16x16x32_bf16(a, b, c, 0, 0, 0);
}

// ---- workspace layout (bytes) -------------------------------------------
//    0 : coefB f32[289] = A_off (diag zeroed)  -> full-path mixing coefs
// 1200 : flag  f32 at ws[300] = 1.0 iff max|A_off| < 1.25e-6
// 2048 : dMb  bf16[17*128] = Adiag[j]*M[j,g]
// 16384: WT   bf16[2][128][128], WT[mat][g][k] = bf16(W[mat][k][g])
__global__ void prep(const float* __restrict__ W, const float* __restrict__ Mw,
                     const float* __restrict__ adj, const float* __restrict__ adj2,
                     float* __restrict__ ws) {
    unsigned short* WT  = (unsigned short*)((char*)ws + 16384);
    unsigned short* dMb = (unsigned short*)((char*)ws + 2048);
    int t = blockIdx.x * 256 + threadIdx.x;
    for (int idx = t; idx < 2 * F * F; idx += 16 * 256) {
        int mat = idx >> 14;
        int rem = idx & 16383;
        int g = rem >> 7, k = rem & 127;
        WT[idx] = f2bf(W[mat * 16384 + k * F + g]);
    }
    if (blockIdx.x == 0) {
        for (int idx = threadIdx.x; idx < J * J; idx += 256) {
            int i = idx / J, j = idx % J;
            float a = 0.5f * (adj[i*J+j] + adj2[i*J+j] + adj[j*J+i] + adj2[j*J+i]);
            ws[idx] = (i == j) ? 0.0f : a;
        }
        for (int idx = threadIdx.x; idx < J * F; idx += 256) {
            int j = idx >> 7;
            float adg = adj[j*J+j] + adj2[j*J+j];   // symmetrized diagonal
            dMb[idx] = f2bf(adg * Mw[idx]);
        }
        // flag: wave-parallel max-reduce over the 289 off-diag entries
        if (threadIdx.x < 64) {
            float mx = 0.0f;
            for (int idx = threadIdx.x; idx < J * J; idx += 64) {
                int i = idx / J, j = idx % J;
                if (i != j) {
                    float a = 0.5f * (adj[i*J+j] + adj2[i*J+j] + adj[j*J+i] + adj2[j*J+i]);
                    mx = fmaxf(mx, __builtin_fabsf(a));
                }
            }
#pragma unroll
            for (int o = 32; o; o >>= 1) mx = fmaxf(mx, __shfl_xor(mx, o, 64));
            if (threadIdx.x == 0) ws[300] = (mx < 1.25e-6f) ? 1.0f : 0.0f;
        }
    }
}

// ==================== FAST kernel: j-partitioned, W0 in LDS ====================
// Wave w handles j in {w, w+4, w+8, w+12} (+ j16 for wave blockIdx&3).
// Per lane: batch = lane&15, k-octet select = lane>>4.
// W0 (32KB bf16), dM, bias staged in LDS once -> mt loop has ZERO global ops.

__device__ __forceinline__ void loadx(const float* xrow, int j, int lq, uint4* q) {
    const uint4* xp = (const uint4*)(xrow + j * F) + lq * 2;
#pragma unroll
    for (int ks = 0; ks < 4; ++ks) { q[2*ks] = xp[ks*8]; q[2*ks+1] = xp[ks*8+1]; }
}
__device__ __forceinline__ void cvt_x(const uint4* q, bf16x8* xf) {
#pragma unroll
    for (int ks = 0; ks < 4; ++ks) {
        uint4 t;
        t.x = pkbf(q[2*ks].x,   q[2*ks].y);
        t.y = pkbf(q[2*ks].z,   q[2*ks].w);
        t.z = pkbf(q[2*ks+1].x, q[2*ks+1].y);
        t.w = pkbf(q[2*ks+1].z, q[2*ks+1].w);
        xf[ks] = __builtin_bit_cast(bf16x8, t);
    }
}

__device__ __forceinline__ void compute_j(const unsigned char* Wl,
        const unsigned short* dMl, const float* biasl, float* orow,
        int j, const bf16x8* xf, int lrow, int lq) {
    const unsigned key = (unsigned)((lrow & 7) << 4);
#pragma unroll
    for (int mtp = 0; mtp < 4; ++mtp) {
        const unsigned rb0 = (unsigned)(((mtp * 2)     * 16 + lrow) * 256);
        const unsigned rb1 = (unsigned)(((mtp * 2 + 1) * 16 + lrow) * 256);
        f32x4 h0 = {0.f,0.f,0.f,0.f}, h1 = {0.f,0.f,0.f,0.f};
#pragma unroll
        for (int ks = 0; ks < 4; ++ks) {
            unsigned cb = (unsigned)(ks * 64 + lq * 16) ^ key;
            bf16x8 w0 = __builtin_bit_cast(bf16x8, *(const uint4*)(Wl + rb0 + cb));
            bf16x8 w1 = __builtin_bit_cast(bf16x8, *(const uint4*)(Wl + rb1 + cb));
            h0 = mfma16(w0, xf[ks], h0);     // two independent chains -> ILP
            h1 = mfma16(w1, xf[ks], h1);
        }
        const int go0 = (mtp * 2) * 16 + lq * 4, go1 = go0 + 16;
        f32x4 b0 = *(const f32x4*)(biasl + go0);
        f32x4 b1 = *(const f32x4*)(biasl + go1);
        f32x4 d0 = bf4(*(const ushort4*)(dMl + j * F + go0));
        f32x4 d1 = bf4(*(const ushort4*)(dMl + j * F + go1));
        *(f32x4*)(orow + j * F + go0) = __builtin_elementwise_fma(d0, h0, b0);
        *(f32x4*)(orow + j * F + go1) = __builtin_elementwise_fma(d1, h1, b1);
    }
}

__global__ __launch_bounds__(256, 2) void mgcn_fast(
    const float* __restrict__ x, const float* __restrict__ bias,
    const float* __restrict__ ws, float* __restrict__ out) {
    if (ws[300] == 0.0f) return;    // off-diag significant -> full kernel handles

    __shared__ __align__(16) unsigned char   Wl[32768];   // W0 bf16 [g][k], swizzled
    __shared__ __align__(16) unsigned short dMl[J * F];   // 4352 B
    __shared__ __align__(16) float         biasl[F];      //  512 B  -> 37632 total

    const int tid  = threadIdx.x;
    const int wv   = tid >> 6;
    const int lane = tid & 63;
    const int lrow = lane & 15;
    const int lq   = lane >> 4;
    const int b0   = blockIdx.x * TB;
    const float* xrow = x   + (size_t)(b0 + lrow) * (J * F);
    float*       orow = out + (size_t)(b0 + lrow) * (J * F);

    // ---- stage W0 (XOR-swizzled), dM, bias; issue first x loads in parallel ----
    uint4 rawA[8], rawB[8];
    loadx(xrow, wv, lq, rawA);
    loadx(xrow, wv + 4, lq, rawB);

    const uint4* wsrc = (const uint4*)((const char*)ws + 16384);   // W0 = first 32KB
#pragma unroll
    for (int c8 = 0; c8 < 8; ++c8) {
        int c = c8 * 256 + tid;                 // 16B chunk index, 2048 total
        uint4 v = wsrc[c];
        unsigned row  = (unsigned)c >> 4;       // g row (256B each)
        unsigned colb = ((unsigned)c & 15) << 4;
        *(uint4*)(Wl + row * 256 + (colb ^ ((row & 7) << 4))) = v;
    }
    {
        const uint4* s = (const uint4*)((const char*)ws + 2048);
        for (int c = tid; c < 272; c += 256) ((uint4*)dMl)[c] = s[c];
    }
    if (tid < 32) ((uint4*)biasl)[tid] = ((const uint4*)bias)[tid];
    __syncthreads();

    // ---- j loop: 2 x-rows in registers, prefetch j+8 after each cvt ----
    bf16x8 xf[4];
#pragma unroll
    for (int i = 0; i < 4; ++i) {
        uint4* cur = (i & 1) ? rawB : rawA;     // static after full unroll
        cvt_x(cur, xf);
        if (i < 2) loadx(xrow, wv + (i + 2) * 4, lq, cur);
        compute_j(Wl, dMl, biasl, orow, wv + i * 4, xf, lrow, lq);
    }
    if (wv == (int)(blockIdx.x & 3)) {          // tail j16, one wave per block
        loadx(xrow, 16, lq, rawA);
        cvt_x(rawA, xf);
        compute_j(Wl, dMl, biasl, orow, 16, xf, lrow, lq);
    }
}

// ==================== FULL kernel: r10 structure (g-partition, LDS) ==========
__global__ __launch_bounds__(512, 2) void mgcn_full(
    const float* __restrict__ x, const float* __restrict__ Mw,
    const float* __restrict__ bias, const float* __restrict__ ws,
    float* __restrict__ out) {
    if (ws[300] != 0.0f) return;    // fast kernel handled it

    __shared__ __align__(16) unsigned char xs[TB * J * F * 2];   // 69632 B
    __shared__ __align__(16) unsigned short dMs[J * F];          //  4352 B

    const int tid  = threadIdx.x;
    const int b0   = blockIdx.x * TB;
    const int wave = tid >> 6;
    const int lane = tid & 63;
    const int lrow = lane & 15;
    const int lq   = lane >> 4;
    const int grow = wave * 16 + lrow;
    const int gq   = wave * 16 + lq * 4;
    const unsigned short* WT = (const unsigned short*)((const char*)ws + 16384);

    const float4* xg = (const float4*)(x + (size_t)b0 * (J * F));
    float4 s1[9], s2[8];
#pragma unroll
    for (int it = 0; it < 9; ++it) {
        int fi = it * 512 + tid;
        int b = fi / 288, r = fi - b * 288;
        s1[it] = xg[b * 544 + r];
    }
#pragma unroll
    for (int it = 0; it < 8; ++it) {
        int fi = it * 512 + tid;
        int b = fi >> 8, r = fi & 255;
        s2[it] = xg[b * 544 + 288 + r];
    }
    if (tid < 272)
        ((uint4*)dMs)[tid] = ((const uint4*)((const char*)ws + 2048))[tid];

    const f32x4 bias4 = *(const f32x4*)(bias + gq);

#pragma unroll
    for (int it = 0; it < 9; ++it) {
        int fi = it * 512 + tid;
        int b = fi / 288, r = fi - b * 288;
        int j = r >> 5, k4 = r & 31;
        unsigned byte = (unsigned)(b * 4352 + j * 256 + k4 * 8)
                      ^ (unsigned)((b & 7) << 4);
        uint4 u = __builtin_bit_cast(uint4, s1[it]);
        uint2 p; p.x = pkbf(u.x, u.y); p.y = pkbf(u.z, u.w);
        *(uint2*)(xs + byte) = p;
    }
#pragma unroll
    for (int it = 0; it < 8; ++it) {
        int fi = it * 512 + tid;
        int b = fi >> 8, r = fi & 255;
        int j = 9 + (r >> 5), k4 = r & 31;
        unsigned byte = (unsigned)(b * 4352 + j * 256 + k4 * 8)
                      ^ (unsigned)((b & 7) << 4);
        uint4 u = __builtin_bit_cast(uint4, s2[it]);
        uint2 p; p.x = pkbf(u.x, u.y); p.y = pkbf(u.z, u.w);
        *(uint2*)(xs + byte) = p;
    }
    __syncthreads();

    const unsigned rbase = (unsigned)(lrow * 4352);
    const unsigned swz   = (unsigned)((lrow & 7) << 4);
    float* ob = out + ((size_t)(b0 + lrow) * J) * F + gq;

    f32x4 acc[J];
#pragma unroll
    for (int i = 0; i < J; ++i) acc[i] = bias4;

    {   // pass B: off-diagonal (wf1 only live); M from global (L2-hot)
        bf16x8 wf[4];
#pragma unroll
        for (int ks = 0; ks < 4; ++ks)
            wf[ks] = __builtin_bit_cast(bf16x8,
                *(const uint4*)(WT + (size_t)(F * F) + (size_t)grow * F + ks * 32 + lq * 8));
#pragma unroll
        for (int j = 0; j < J; ++j) {
            f32x4 h1 = {0.f,0.f,0.f,0.f};
#pragma unroll
            for (int ks = 0; ks < 4; ++ks) {
                unsigned byte = (rbase + (unsigned)(j * 256 + ks * 64 + lq * 16)) ^ swz;
                bf16x8 xf = __builtin_bit_cast(bf16x8, *(const uint4*)(xs + byte));
                h1 = __builtin_amdgcn_mfma_f32_16x16x32_bf16(wf[ks], xf, h1, 0, 0, 0);
            }
            f32x4 mj  = *(const f32x4*)&Mw[j * F + gq];
            f32x4 mh1 = mj * h1;
#pragma unroll
            for (int i = 0; i < J; ++i)
                acc[i] = fma4(ws[i * J + j], mh1, acc[i]);
        }
    }
    {   // pass A: diagonal (wf0 only live); acc[j] dies at its store
        bf16x8 wf[4];
#pragma unroll
        for (int ks = 0; ks < 4; ++ks)
            wf[ks] = __builtin_bit_cast(bf16x8,
                *(const uint4*)(WT + (size_t)grow * F + ks * 32 + lq * 8));
#pragma unroll
        for (int j = 0; j < J; ++j) {
            f32x4 h0 = {0.f,0.f,0.f,0.f};
#pragma unroll
            for (int ks = 0; ks < 4; ++ks) {
                unsigned byte = (rbase + (unsigned)(j * 256 + ks * 64 + lq * 16)) ^ swz;
                bf16x8 xf = __builtin_bit_cast(bf16x8, *(const uint4*)(xs + byte));
                h0 = __builtin_amdgcn_mfma_f32_16x16x32_bf16(wf[ks], xf, h0, 0, 0, 0);
            }
            f32x4 dj = bf4(*(const ushort4*)(dMs + j * F + gq));
            acc[j] = __builtin_elementwise_fma(dj, h0, acc[j]);
            *(f32x4*)(ob + (size_t)j * F) = acc[j];
        }
    }
}

extern "C" void kernel_launch(void* const* d_in, const int* in_sizes, int n_in,
                              void* d_out, int out_size, void* d_ws, size_t ws_size,
                              hipStream_t stream) {
    const float* x    = (const float*)d_in[0];
    const float* W    = (const float*)d_in[1];
    const float* Mw   = (const float*)d_in[2];
    const float* adj  = (const float*)d_in[3];
    const float* adj2 = (const float*)d_in[4];
    const float* bias = (const float*)d_in[5];
    float* out = (float*)d_out;
    float* ws  = (float*)d_ws;   // needs >= 81920 B

    int Btot = in_sizes[0] / (J * F);   // 16384
    prep<<<16, 256, 0, stream>>>(W, Mw, adj, adj2, ws);
    mgcn_fast<<<Btot / TB, 256, 0, stream>>>(x, bias, ws, out);
    mgcn_full<<<Btot / TB, 512, 0, stream>>>(x, Mw, bias, ws, out);
}

// Round 16
// 83.367 us; speedup vs baseline: 1.2068x; 1.2068x over previous
//
#include <hip/hip_runtime.h>

#define J 17
#define F 128
#define TB 16

typedef __attribute__((ext_vector_type(4))) float f32x4;
typedef __attribute__((ext_vector_type(8))) short bf16x8;   // 8 bf16 in 4 VGPRs

__device__ __forceinline__ unsigned short f2bf(float f) {
    unsigned u = __builtin_bit_cast(unsigned, f);
    u += 0x7fffu + ((u >> 16) & 1u);
    return (unsigned short)(u >> 16);
}
__device__ __forceinline__ float bf2f(unsigned short s) {
    return __builtin_bit_cast(float, (unsigned)s << 16);
}
// pack two f32 (raw bits) -> two bf16, round-half-up: 2 v_add + 1 v_perm
__device__ __forceinline__ unsigned pkbf(unsigned lo, unsigned hi) {
    return __builtin_amdgcn_perm(hi + 0x8000u, lo + 0x8000u, 0x07060302u);
}
__device__ __forceinline__ f32x4 fma4(float a, f32x4 v, f32x4 c) {
    f32x4 av = {a, a, a, a};
    return __builtin_elementwise_fma(av, v, c);
}
__device__ __forceinline__ f32x4 bf4(ushort4 u) {
    return (f32x4){bf2f(u.x), bf2f(u.y), bf2f(u.z), bf2f(u.w)};
}
__device__ __forceinline__ f32x4 mfma16(bf16x8 a, bf16x8 b, f32x4 c) {
    return __builtin_amdgcn_mfma_f32_16x16x32_bf16(a, b, c, 0, 0, 0);
}

// ---- workspace layout (bytes) -------------------------------------------
//    0 : coefB f32[289] = A_off (diag zeroed)
// 1200 : flag  f32 at ws[300] = 1.0 iff max|A_off| < 1.25e-6
// 2048 : dMb  bf16[17*128] = Adiag[j]*M[j,g]
// 16384: WT   bf16[2][128][128], WT[mat][g][k] = bf16(W[mat][k][g])
__global__ void prep(const float* __restrict__ W, const float* __restrict__ Mw,
                     const float* __restrict__ adj, const float* __restrict__ adj2,
                     float* __restrict__ ws) {
    unsigned short* WT  = (unsigned short*)((char*)ws + 16384);
    unsigned short* dMb = (unsigned short*)((char*)ws + 2048);
    int t = blockIdx.x * 256 + threadIdx.x;
    for (int idx = t; idx < 2 * F * F; idx += 16 * 256) {
        int mat = idx >> 14;
        int rem = idx & 16383;
        int g = rem >> 7, k = rem & 127;
        WT[idx] = f2bf(W[mat * 16384 + k * F + g]);
    }
    if (blockIdx.x == 0) {
        for (int idx = threadIdx.x; idx < J * J; idx += 256) {
            int i = idx / J, j = idx % J;
            float a = 0.5f * (adj[i*J+j] + adj2[i*J+j] + adj[j*J+i] + adj2[j*J+i]);
            ws[idx] = (i == j) ? 0.0f : a;
        }
        for (int idx = threadIdx.x; idx < J * F; idx += 256) {
            int j = idx >> 7;
            float adg = adj[j*J+j] + adj2[j*J+j];
            dMb[idx] = f2bf(adg * Mw[idx]);
        }
        if (threadIdx.x < 64) {
            float mx = 0.0f;
            for (int idx = threadIdx.x; idx < J * J; idx += 64) {
                int i = idx / J, j = idx % J;
                if (i != j) {
                    float a = 0.5f * (adj[i*J+j] + adj2[i*J+j] + adj[j*J+i] + adj2[j*J+i]);
                    mx = fmaxf(mx, __builtin_fabsf(a));
                }
            }
#pragma unroll
            for (int o = 32; o; o >>= 1) mx = fmaxf(mx, __shfl_xor(mx, o, 64));
            if (threadIdx.x == 0) ws[300] = (mx < 1.25e-6f) ? 1.0f : 0.0f;
        }
    }
}

// ============ FAST kernel: flattened rows, barrier-free tile pipeline ========
// 278528 flat rows (b*17+j); tile = 16 consecutive rows; wave -> 4 tiles.
// W0 (swizzled) + dM + bias in LDS once per block. Per lane: row = tile*16 +
// (lane&15), k-octets at ks*32 + (lane>>4)*8.

__device__ __forceinline__ void loadtile(const float* __restrict__ x,
                                         int t, int lrow, int lq, uint4* q) {
    const uint4* p = (const uint4*)(x + (size_t)(t * 16 + lrow) * F) + lq * 2;
#pragma unroll
    for (int ks = 0; ks < 4; ++ks) { q[2*ks] = p[ks*8]; q[2*ks+1] = p[ks*8+1]; }
}
__device__ __forceinline__ void cvt_x(const uint4* q, bf16x8* xf) {
#pragma unroll
    for (int ks = 0; ks < 4; ++ks) {
        uint4 t;
        t.x = pkbf(q[2*ks].x,   q[2*ks].y);
        t.y = pkbf(q[2*ks].z,   q[2*ks].w);
        t.z = pkbf(q[2*ks+1].x, q[2*ks+1].y);
        t.w = pkbf(q[2*ks+1].z, q[2*ks+1].w);
        xf[ks] = __builtin_bit_cast(bf16x8, t);
    }
}

__device__ __forceinline__ void compute_tile(const unsigned char* Wl,
        const unsigned short* dMl, const float* biasl, float* __restrict__ out,
        int t, const bf16x8* xf, int lrow, int lq) {
    const unsigned flat = (unsigned)(t * 16 + lrow);
    // FIXED: flat%17 via 64-bit magic (old 32-bit mul overflowed for flat>=~69650)
    const unsigned q17  = (unsigned)(((unsigned long long)flat * 0xF0F0F0F1ull) >> 36);
    const unsigned j    = flat - 17u * q17;
    float* orow = out + (size_t)flat * F;
    const unsigned key = (unsigned)((lrow & 7) << 4);
#pragma unroll
    for (int mt = 0; mt < 8; ++mt) {
        const unsigned rb = (unsigned)((mt * 16 + lrow) * 256);
        f32x4 h = {0.f, 0.f, 0.f, 0.f};
#pragma unroll
        for (int ks = 0; ks < 4; ++ks) {
            unsigned cb = (unsigned)(ks * 64 + lq * 16) ^ key;
            bf16x8 w = __builtin_bit_cast(bf16x8, *(const uint4*)(Wl + rb + cb));
            h = mfma16(w, xf[ks], h);
        }
        const int go = mt * 16 + lq * 4;
        f32x4 b4 = *(const f32x4*)(biasl + go);
        f32x4 d  = bf4(*(const ushort4*)(dMl + j * F + go));
        *(f32x4*)(orow + go) = __builtin_elementwise_fma(d, h, b4);
    }
}

__global__ __launch_bounds__(256, 2) void mgcn_fast(
    const float* __restrict__ x, const float* __restrict__ bias,
    const float* __restrict__ ws, float* __restrict__ out) {
    if (ws[300] == 0.0f) return;    // off-diag significant -> full kernel handles

    __shared__ __align__(16) unsigned char   Wl[32768];   // W0 bf16 [g][k] swizzled
    __shared__ __align__(16) unsigned short dMl[J * F];   // 4352 B
    __shared__ __align__(16) float         biasl[F];      //  512 B

    const int tid  = threadIdx.x;
    const int wv   = tid >> 6;
    const int lane = tid & 63;
    const int lrow = lane & 15;
    const int lq   = lane >> 4;
    const int t0   = (blockIdx.x * 4 + wv) * 4;   // 4 consecutive tiles per wave

    // issue first two tiles' x loads BEFORE staging (latency hides under it)
    uint4 bufA[8], bufB[8];
    loadtile(x, t0 + 0, lrow, lq, bufA);
    loadtile(x, t0 + 1, lrow, lq, bufB);

    // stage W0 (XOR-swizzled), dM, bias
    const uint4* wsrc = (const uint4*)((const char*)ws + 16384);
#pragma unroll
    for (int c8 = 0; c8 < 8; ++c8) {
        int c = c8 * 256 + tid;                 // 2048 16B chunks
        uint4 v = wsrc[c];
        unsigned row  = (unsigned)c >> 4;
        unsigned colb = ((unsigned)c & 15) << 4;
        *(uint4*)(Wl + row * 256 + (colb ^ ((row & 7) << 4))) = v;
    }
    {
        const uint4* s = (const uint4*)((const char*)ws + 2048);
        for (int c = tid; c < 272; c += 256) ((uint4*)dMl)[c] = s[c];
    }
    if (tid < 32) ((uint4*)biasl)[tid] = ((const uint4*)bias)[tid];
    __syncthreads();

    // barrier-free pipeline: cvt frees buf -> reissue -> compute
    bf16x8 xf[4];
    cvt_x(bufA, xf);
    loadtile(x, t0 + 2, lrow, lq, bufA);
    compute_tile(Wl, dMl, biasl, out, t0 + 0, xf, lrow, lq);

    cvt_x(bufB, xf);
    loadtile(x, t0 + 3, lrow, lq, bufB);
    compute_tile(Wl, dMl, biasl, out, t0 + 1, xf, lrow, lq);

    cvt_x(bufA, xf);
    compute_tile(Wl, dMl, biasl, out, t0 + 2, xf, lrow, lq);

    cvt_x(bufB, xf);
    compute_tile(Wl, dMl, biasl, out, t0 + 3, xf, lrow, lq);
}

// ==================== FULL kernel: r10/r13 structure (passed) ================
__global__ __launch_bounds__(512, 2) void mgcn_full(
    const float* __restrict__ x, const float* __restrict__ Mw,
    const float* __restrict__ bias, const float* __restrict__ ws,
    float* __restrict__ out) {
    if (ws[300] != 0.0f) return;    // fast kernel handled it

    __shared__ __align__(16) unsigned char xs[TB * J * F * 2];   // 69632 B
    __shared__ __align__(16) unsigned short dMs[J * F];          //  4352 B

    const int tid  = threadIdx.x;
    const int b0   = blockIdx.x * TB;
    const int wave = tid >> 6;
    const int lane = tid & 63;
    const int lrow = lane & 15;
    const int lq   = lane >> 4;
    const int grow = wave * 16 + lrow;
    const int gq   = wave * 16 + lq * 4;
    const unsigned short* WT = (const unsigned short*)((const char*)ws + 16384);

    const float4* xg = (const float4*)(x + (size_t)b0 * (J * F));
    float4 s1[9], s2[8];
#pragma unroll
    for (int it = 0; it < 9; ++it) {
        int fi = it * 512 + tid;
        int b = fi / 288, r = fi - b * 288;
        s1[it] = xg[b * 544 + r];
    }
#pragma unroll
    for (int it = 0; it < 8; ++it) {
        int fi = it * 512 + tid;
        int b = fi >> 8, r = fi & 255;
        s2[it] = xg[b * 544 + 288 + r];
    }
    if (tid < 272)
        ((uint4*)dMs)[tid] = ((const uint4*)((const char*)ws + 2048))[tid];

    const f32x4 bias4 = *(const f32x4*)(bias + gq);

#pragma unroll
    for (int it = 0; it < 9; ++it) {
        int fi = it * 512 + tid;
        int b = fi / 288, r = fi - b * 288;
        int j = r >> 5, k4 = r & 31;
        unsigned byte = (unsigned)(b * 4352 + j * 256 + k4 * 8)
                      ^ (unsigned)((b & 7) << 4);
        uint4 u = __builtin_bit_cast(uint4, s1[it]);
        uint2 p; p.x = pkbf(u.x, u.y); p.y = pkbf(u.z, u.w);
        *(uint2*)(xs + byte) = p;
    }
#pragma unroll
    for (int it = 0; it < 8; ++it) {
        int fi = it * 512 + tid;
        int b = fi >> 8, r = fi & 255;
        int j = 9 + (r >> 5), k4 = r & 31;
        unsigned byte = (unsigned)(b * 4352 + j * 256 + k4 * 8)
                      ^ (unsigned)((b & 7) << 4);
        uint4 u = __builtin_bit_cast(uint4, s2[it]);
        uint2 p; p.x = pkbf(u.x, u.y); p.y = pkbf(u.z, u.w);
        *(uint2*)(xs + byte) = p;
    }
    __syncthreads();

    const unsigned rbase = (unsigned)(lrow * 4352);
    const unsigned swz   = (unsigned)((lrow & 7) << 4);
    float* ob = out + ((size_t)(b0 + lrow) * J) * F + gq;

    f32x4 acc[J];
#pragma unroll
    for (int i = 0; i < J; ++i) acc[i] = bias4;

    {   // pass B: off-diagonal (wf1 only live)
        bf16x8 wf[4];
#pragma unroll
        for (int ks = 0; ks < 4; ++ks)
            wf[ks] = __builtin_bit_cast(bf16x8,
                *(const uint4*)(WT + (size_t)(F * F) + (size_t)grow * F + ks * 32 + lq * 8));
#pragma unroll
        for (int j = 0; j < J; ++j) {
            f32x4 h1 = {0.f,0.f,0.f,0.f};
#pragma unroll
            for (int ks = 0; ks < 4; ++ks) {
                unsigned byte = (rbase + (unsigned)(j * 256 + ks * 64 + lq * 16)) ^ swz;
                bf16x8 xf = __builtin_bit_cast(bf16x8, *(const uint4*)(xs + byte));
                h1 = __builtin_amdgcn_mfma_f32_16x16x32_bf16(wf[ks], xf, h1, 0, 0, 0);
            }
            f32x4 mj  = *(const f32x4*)&Mw[j * F + gq];
            f32x4 mh1 = mj * h1;
#pragma unroll
            for (int i = 0; i < J; ++i)
                acc[i] = fma4(ws[i * J + j], mh1, acc[i]);
        }
    }
    {   // pass A: diagonal (wf0 only live)
        bf16x8 wf[4];
#pragma unroll
        for (int ks = 0; ks < 4; ++ks)
            wf[ks] = __builtin_bit_cast(bf16x8,
                *(const uint4*)(WT + (size_t)grow * F + ks * 32 + lq * 8));
#pragma unroll
        for (int j = 0; j < J; ++j) {
            f32x4 h0 = {0.f,0.f,0.f,0.f};
#pragma unroll
            for (int ks = 0; ks < 4; ++ks) {
                unsigned byte = (rbase + (unsigned)(j * 256 + ks * 64 + lq * 16)) ^ swz;
                bf16x8 xf = __builtin_bit_cast(bf16x8, *(const uint4*)(xs + byte));
                h0 = __builtin_amdgcn_mfma_f32_16x16x32_bf16(wf[ks], xf, h0, 0, 0, 0);
            }
            f32x4 dj = bf4(*(const ushort4*)(dMs + j * F + gq));
            acc[j] = __builtin_elementwise_fma(dj, h0, acc[j]);
            *(f32x4*)(ob + (size_t)j * F) = acc[j];
        }
    }
}

extern "C" void kernel_launch(void* const* d_in, const int* in_sizes, int n_in,
                              void* d_out, int out_size, void* d_ws, size_t ws_size,
                              hipStream_t stream) {
    const float* x    = (const float*)d_in[0];
    const float* W    = (const float*)d_in[1];
    const float* Mw   = (const float*)d_in[2];
    const float* adj  = (const float*)d_in[3];
    const float* adj2 = (const float*)d_in[4];
    const float* bias = (const float*)d_in[5];
    float* out = (float*)d_out;
    float* ws  = (float*)d_ws;   // needs >= 81920 B

    int Btot = in_sizes[0] / (J * F);        // 16384
    int tiles = Btot * J / 16;               // 17408 flat row-tiles
    prep<<<16, 256, 0, stream>>>(W, Mw, adj, adj2, ws);
    mgcn_fast<<<tiles / 16, 256, 0, stream>>>(x, bias, ws, out);   // 1088 blocks
    mgcn_full<<<Btot / TB, 512, 0, stream>>>(x, Mw, bias, ws, out);
}